// Round 3
// baseline (246.750 us; speedup 1.0000x reference)
//
#include <hip/hip_runtime.h>
#include <hip/hip_bf16.h>

#define RANK 16
#define EMBED_DIM 128

// ---------------------------------------------------------------------------
// Workspace layout (u32 units):
//   flag[1] | counts[N] | offsets[N] | cursors[N] | partials[1024] | csr_src[E]
// Only flag+counts need zeroing (one memset).
// ---------------------------------------------------------------------------

// K1: detect edge_index element width. int64 layout => odd 32-bit words are
// high halves of node ids => all zero. int32 => random ids => nonzero.
__global__ void detect_idx_dtype(const unsigned int* __restrict__ words,
                                 int nwords, int* __restrict__ flag) {
    unsigned int v = 0;
    for (int i = threadIdx.x; i < 2048; i += 256) {
        int w = 2 * i + 1;
        if (w < nwords) v |= words[w];
    }
    if (__any(v != 0)) {
        if ((threadIdx.x & 63) == 0) atomicOr(flag, 1);
    }
}

// K2: degree histogram (int atomics, 640K total).
__global__ void hist_kernel(const void* __restrict__ ei,
                            const int* __restrict__ flag,
                            unsigned* __restrict__ counts, int E) {
    int e = blockIdx.x * 256 + threadIdx.x;
    if (e >= E) return;
    int dst;
    if (*flag) dst = ((const int*)ei)[E + e];
    else       dst = ((const int*)ei)[2 * (E + e)];   // int64 low word
    atomicAdd(&counts[dst], 1u);
}

// K3a: per-block exclusive scan of counts -> offsets; block sums -> partials.
__global__ void scan1(const unsigned* __restrict__ counts,
                      unsigned* __restrict__ offsets,
                      unsigned* __restrict__ partials, int N) {
    __shared__ unsigned s[256];
    int t = threadIdx.x;
    int i = blockIdx.x * 256 + t;
    unsigned v = (i < N) ? counts[i] : 0u;
    s[t] = v; __syncthreads();
    for (int off = 1; off < 256; off <<= 1) {
        unsigned x = (t >= off) ? s[t - off] : 0u;
        __syncthreads();
        s[t] += x; __syncthreads();
    }
    if (i < N) offsets[i] = s[t] - v;          // exclusive within block
    if (t == 255) partials[blockIdx.x] = s[255];
}

// K3b: exclusive scan of block partials (P <= 1024, one block).
__global__ void scan2(unsigned* __restrict__ partials, int P) {
    __shared__ unsigned s[1024];
    int t = threadIdx.x;
    unsigned v = (t < P) ? partials[t] : 0u;
    s[t] = v; __syncthreads();
    for (int off = 1; off < 1024; off <<= 1) {
        unsigned x = (t >= off) ? s[t - off] : 0u;
        __syncthreads();
        s[t] += x; __syncthreads();
    }
    if (t < P) partials[t] = s[t] - v;         // exclusive
}

// K3c: add block bases; duplicate offsets into cursors for the fill pass.
__global__ void scan3(unsigned* __restrict__ offsets,
                      unsigned* __restrict__ cursors,
                      const unsigned* __restrict__ partials, int N) {
    int i = blockIdx.x * 256 + threadIdx.x;
    if (i >= N) return;
    unsigned o = offsets[i] + partials[blockIdx.x];
    offsets[i] = o;
    cursors[i] = o;
}

// K4: scatter src ids into CSR slots (int atomics, 640K total).
__global__ void fill_kernel(const void* __restrict__ ei,
                            const int* __restrict__ flag,
                            unsigned* __restrict__ cursors,
                            unsigned* __restrict__ csr_src, int E) {
    int e = blockIdx.x * 256 + threadIdx.x;
    if (e >= E) return;
    int src, dst;
    if (*flag) { const int* p = (const int*)ei; src = p[e];     dst = p[E + e]; }
    else       { const int* p = (const int*)ei; src = p[2 * e]; dst = p[2 * (E + e)]; }
    unsigned pos = atomicAdd(&cursors[dst], 1u);
    csr_src[pos] = (unsigned)src;
}

// K5: fused gather + project. Block = 256 threads handles 32 nodes.
// Phase 1: 16 lane-groups sum U[src] rows (coalesced 64B reads) into LDS.
// Phase 2: each thread computes 4x float4 output columns for one node from
// LDS usum (+17 pad, conflict-free broadcast) and LDS-staged V; float4 stores.
__global__ __launch_bounds__(256) void gather_project(
        const float* __restrict__ U, const float* __restrict__ V,
        const unsigned* __restrict__ counts,
        const unsigned* __restrict__ offsets,
        const unsigned* __restrict__ csr_src,
        float* __restrict__ out, int N) {
    __shared__ float4 Vs4[RANK * EMBED_DIM / 4];   // 8 KB
    __shared__ float usum[32][RANK + 1];           // padded: conflict-free
    int t = threadIdx.x;
    const float4* V4 = (const float4*)V;
    Vs4[t] = V4[t];
    Vs4[t + 256] = V4[t + 256];

    // phase 1
    int g = t >> 4, lane = t & 15;
    for (int rep = 0; rep < 2; ++rep) {
        int ln = rep * 16 + g;                     // local node 0..31
        int n = blockIdx.x * 32 + ln;
        float acc = 0.f;
        if (n < N) {
            unsigned start = offsets[n];
            unsigned deg = counts[n];
            for (unsigned k = 0; k < deg; ++k) {
                unsigned src = csr_src[start + k];
                acc += U[(size_t)src * RANK + lane];
            }
        }
        usum[ln][lane] = acc;
    }
    __syncthreads();

    // phase 2
    int ln = t >> 3;                               // 0..31
    int c8 = t & 7;                                // 0..7
    int n = blockIdx.x * 32 + ln;
    if (n >= N) return;
    float a[RANK];
#pragma unroll
    for (int k = 0; k < RANK; ++k) a[k] = usum[ln][k];
    float deg = (float)counts[n];
    float scale = 1.0f / fmaxf(deg, 1.0f);
    float4* out4 = (float4*)out;
#pragma unroll
    for (int s = 0; s < 4; ++s) {
        int c4 = c8 + 8 * s;
        float4 acc = make_float4(0.f, 0.f, 0.f, 0.f);
#pragma unroll
        for (int k = 0; k < RANK; ++k) {
            float4 v = Vs4[k * 32 + c4];
            acc.x = fmaf(a[k], v.x, acc.x);
            acc.y = fmaf(a[k], v.y, acc.y);
            acc.z = fmaf(a[k], v.z, acc.z);
            acc.w = fmaf(a[k], v.w, acc.w);
        }
        out4[(size_t)n * (EMBED_DIM / 4) + c4] =
            make_float4(acc.x * scale, acc.y * scale, acc.z * scale, acc.w * scale);
    }
}

extern "C" void kernel_launch(void* const* d_in, const int* in_sizes, int n_in,
                              void* d_out, int out_size, void* d_ws, size_t ws_size,
                              hipStream_t stream) {
    const float* U = (const float*)d_in[0];
    const float* V = (const float*)d_in[1];
    const void* EI = d_in[2];
    float* out = (float*)d_out;

    const int N = in_sizes[0] / RANK;      // 200000
    const int E = in_sizes[2] / 2;         // 640000

    unsigned* ws = (unsigned*)d_ws;
    int*      flag     = (int*)ws;
    unsigned* counts   = ws + 1;
    unsigned* offsets  = counts + N;
    unsigned* cursors  = offsets + N;
    unsigned* partials = cursors + N;
    unsigned* csr_src  = partials + 1024;

    const int NB = (N + 255) / 256;        // 782 scan blocks (<= 1024)
    const int EB = (E + 255) / 256;

    hipMemsetAsync(d_ws, 0, sizeof(unsigned) * (size_t)(N + 1), stream);

    detect_idx_dtype<<<1, 256, 0, stream>>>((const unsigned int*)EI,
                                            in_sizes[2], flag);
    hist_kernel<<<EB, 256, 0, stream>>>(EI, flag, counts, E);
    scan1<<<NB, 256, 0, stream>>>(counts, offsets, partials, N);
    scan2<<<1, 1024, 0, stream>>>(partials, NB);
    scan3<<<NB, 256, 0, stream>>>(offsets, cursors, partials, N);
    fill_kernel<<<EB, 256, 0, stream>>>(EI, flag, cursors, csr_src, E);
    gather_project<<<(N + 31) / 32, 256, 0, stream>>>(U, V, counts, offsets,
                                                      csr_src, out, N);
}